// Round 7
// baseline (291.173 us; speedup 1.0000x reference)
//
#include <hip/hip_runtime.h>

// MEASUREMENT ROUND: identical to round-5 kernel (best so far), but the
// fused kernel is dispatched 3x. It is idempotent (plain per-block stores
// to partials, no atomics), so output is unchanged; the two extra (L3-warm)
// runs add 2*K_warm to the harness total, finally measuring the invisible
// kernel: K_warm = (total_R7 - total_R5) / 2.
//
// Fused math: h = relu(X @ M + d), s0 = sum(h), where M = W^T @ RW,
// d = b @ RW + 1 (precomputed by setup_kernel). Then n = #halvings of
// f32(s0) until <= 1; out = f32(s0) * 2^-n (exact power-of-2 scaling).

#define D 20
#define BLOCK 256
#define RPT 2  // rows per thread

// d_ws layout:
//   [0, 32768)          : double partials[4096] (one per block)
//   [32768, +1600)      : float Mt[400], Mt[j*D+k] = M[k][j] (j-major)
//   [+1600, +1680)      : float dvec[20]
#define WS_PARTIALS_BYTES 32768

__global__ void setup_kernel(const float* __restrict__ W,
                             const float* __restrict__ b,
                             const float* __restrict__ RW,
                             float* __restrict__ Mt,
                             float* __restrict__ dvec) {
    const int tid = threadIdx.x;
    for (int idx = tid; idx < D * D; idx += blockDim.x) {
        const int j = idx / D, k = idx % D;
        float s = 0.0f;
        for (int i = 0; i < D; ++i)
            s = fmaf(W[i * D + k], RW[i * D + j], s);
        Mt[idx] = s;  // idx == j*D + k
    }
    if (tid < D) {
        float s = 1.0f;
        for (int i = 0; i < D; ++i)
            s = fmaf(b[i], RW[i * D + tid], s);
        dvec[tid] = s;
    }
}

__global__ void __launch_bounds__(BLOCK)
fused_mlp_sum(const float* __restrict__ X,
              const float* __restrict__ Mt,
              const float* __restrict__ dvec,
              double* __restrict__ partials,
              int nrows) {
    __shared__ float wave_sums[BLOCK / 64];

    const int tid = threadIdx.x;
    const long long t = (long long)blockIdx.x * BLOCK + tid;
    const long long row0 = t * RPT;
    const bool valid = row0 < (long long)nrows;
    // Clamp instead of branch: uniform control flow lets the backend
    // scalarize the Mt/dvec loads (s_load -> SGPR, scalar pipe).
    const long long rbase = valid ? row0 : (long long)nrows - RPT;
    const float* xp = X + rbase * D;

    float x0[D], x1[D];
#pragma unroll
    for (int q = 0; q < 5; ++q) {
        float4 v = ((const float4*)xp)[q];
        x0[4 * q + 0] = v.x; x0[4 * q + 1] = v.y;
        x0[4 * q + 2] = v.z; x0[4 * q + 3] = v.w;
        float4 u = ((const float4*)(xp + D))[q];
        x1[4 * q + 0] = u.x; x1[4 * q + 1] = u.y;
        x1[4 * q + 2] = u.z; x1[4 * q + 3] = u.w;
    }

    float lsum = 0.0f;
#pragma unroll
    for (int j = 0; j < D; ++j) {
        float t0 = dvec[j];   // uniform addr + uniform CF -> s_load (SGPR)
        float t1 = t0;
#pragma unroll
        for (int k = 0; k < D; ++k) {
            const float m = Mt[j * D + k];  // uniform -> s_load, scalar pipe
            t0 = fmaf(x0[k], m, t0);        // v_fma with SGPR src
            t1 = fmaf(x1[k], m, t1);
        }
        lsum += fmaxf(t0, 0.0f) + fmaxf(t1, 0.0f);
    }
    lsum = valid ? lsum : 0.0f;  // mask clamped tail lanes

    // Wave (64-lane) shuffle reduction -> block LDS -> one plain store.
#pragma unroll
    for (int off = 32; off > 0; off >>= 1)
        lsum += __shfl_down(lsum, off, 64);
    if ((tid & 63) == 0) wave_sums[tid >> 6] = lsum;
    __syncthreads();
    if (tid == 0) {
        float bs = 0.0f;
#pragma unroll
        for (int w = 0; w < BLOCK / 64; ++w) bs += wave_sums[w];
        partials[blockIdx.x] = (double)bs;  // idempotent: no atomic
    }
}

__global__ void __launch_bounds__(1024)
finalize_kernel(const double* __restrict__ partials, int nparts,
                float* __restrict__ out) {
    __shared__ double wsum[16];
    const int tid = threadIdx.x;
    double s = 0.0;
    for (int i = tid; i < nparts; i += 1024) s += partials[i];
#pragma unroll
    for (int off = 32; off > 0; off >>= 1)
        s += __shfl_down(s, off, 64);
    if ((tid & 63) == 0) wsum[tid >> 6] = s;
    __syncthreads();
    if (tid == 0) {
        double s0 = 0.0;
#pragma unroll
        for (int w = 0; w < 16; ++w) s0 += wsum[w];
        float f = (float)s0;   // reference's s0 is f32
        int n = 0;
        while (f > 1.0f) { ++n; f *= 0.5f; }  // exact power-of-2 halvings
        out[0] = f;
    }
}

extern "C" void kernel_launch(void* const* d_in, const int* in_sizes, int n_in,
                              void* d_out, int out_size, void* d_ws, size_t ws_size,
                              hipStream_t stream) {
    const float* X  = (const float*)d_in[0];
    const float* W  = (const float*)d_in[1];
    const float* b  = (const float*)d_in[2];
    const float* RW = (const float*)d_in[3];
    float* out = (float*)d_out;

    double* partials = (double*)d_ws;
    float*  Mt = (float*)((char*)d_ws + WS_PARTIALS_BYTES);
    float*  dv = Mt + D * D;

    const int nrows = in_sizes[0] / D;  // 2,000,000

    setup_kernel<<<1, 256, 0, stream>>>(W, b, RW, Mt, dv);

    const long long nthreads = ((long long)nrows + RPT - 1) / RPT;  // 1,000,000
    const int blocks = (int)((nthreads + BLOCK - 1) / BLOCK);       // 3907
    // 3 identical dispatches: run 1 cold, runs 2-3 L3-warm. Idempotent.
    fused_mlp_sum<<<blocks, BLOCK, 0, stream>>>(X, Mt, dv, partials, nrows);
    fused_mlp_sum<<<blocks, BLOCK, 0, stream>>>(X, Mt, dv, partials, nrows);
    fused_mlp_sum<<<blocks, BLOCK, 0, stream>>>(X, Mt, dv, partials, nrows);
    finalize_kernel<<<1, 1024, 0, stream>>>(partials, blocks, out);
}